// Round 7
// baseline (822.869 us; speedup 1.0000x reference)
//
#include <hip/hip_runtime.h>
#include <math.h>

typedef __bf16 bf16x8 __attribute__((ext_vector_type(8)));
typedef __bf16 bf16x4 __attribute__((ext_vector_type(4)));
typedef float  f32x4  __attribute__((ext_vector_type(4)));

constexpr int Bc = 64, Sc = 1024, Dc = 768;
constexpr int ISc = 307, IDc = 230;
constexpr int ISp = 312, IDp = 232;   // padded to x8, zero-filled

static __device__ __forceinline__ float bf2f(unsigned short u) {
    return __builtin_bit_cast(float, (unsigned)u << 16);
}

// ---------------- fused fp32 -> bf16 weight convert (all 4 tensors) --------
// segment chunk counts (8-elem chunks, x10 tasks)
constexpr int CH0 = 10 * ISp * (Sc  / 8);   // w1_tok -> wT1
constexpr int CH1 = 10 * Sc  * (ISp / 8);   // w2_tok -> wT2
constexpr int CH2 = 10 * IDp * (Dc  / 8);   // w1_ch  -> wC1
constexpr int CH3 = 10 * Dc  * (IDp / 8);   // w2_ch  -> wC2
constexpr int CB0 = CH0, CB1 = CB0 + CH1, CB2 = CB1 + CH2, CB3 = CB2 + CH3;

__device__ __forceinline__ void cvt_one(
    const float* __restrict__ in, __bf16* __restrict__ out,
    int inrows, int outrows, int incols, int outcols, int c)
{
    const int cpr  = outcols >> 3;
    const int perT = outrows * cpr;
    const int t    = c / perT;
    const int rem  = c - t * perT;
    const int r    = rem / cpr;
    const int cc   = (rem - r * cpr) * 8;
    bf16x8 o;
    if (r < inrows) {
        const float* src = in + ((long)t * inrows + r) * incols + cc;
        #pragma unroll
        for (int e = 0; e < 8; e++)
            o[e] = (cc + e < incols) ? (__bf16)src[e] : (__bf16)0.0f;
    } else {
        #pragma unroll
        for (int e = 0; e < 8; e++) o[e] = (__bf16)0.0f;
    }
    *reinterpret_cast<bf16x8*>(out + ((long)t * outrows + r) * outcols + cc) = o;
}

__global__ __launch_bounds__(256) void cvt_all(
    const float* __restrict__ w1t, const float* __restrict__ w2t,
    const float* __restrict__ w1c, const float* __restrict__ w2c,
    __bf16* __restrict__ o1t, __bf16* __restrict__ o2t,
    __bf16* __restrict__ o1c, __bf16* __restrict__ o2c)
{
    const int c = blockIdx.x * 256 + threadIdx.x;
    if (c < CB0)      cvt_one(w1t, o1t, ISc, ISp, Sc,  Sc,  c);
    else if (c < CB1) cvt_one(w2t, o2t, Sc,  Sc,  ISc, ISp, c - CB0);
    else if (c < CB2) cvt_one(w1c, o1c, IDc, IDp, Dc,  Dc,  c - CB1);
    else if (c < CB3) cvt_one(w2c, o2c, Dc,  Dc,  IDc, IDp, c - CB2);
}

// ---------------- LN1 fused with transpose: x (B,S,D) fp32 -> h1T (B,D,S) bf16
__global__ __launch_bounds__(256) void ln1_t(
    const float* __restrict__ x, const int* __restrict__ tasks,
    const float* __restrict__ cln, __bf16* __restrict__ h1T)
{
    constexpr int RPB = 32, LDT = Dc + 8;          // 776
    __shared__ unsigned short T[RPB * LDT];        // 48.5 KB
    const int b   = blockIdx.y;
    const int t   = tasks[b];
    const int s0  = blockIdx.x * RPB;
    const int tid = threadIdx.x;
    const int r   = tid >> 3;                      // 0..31
    const int d0  = (tid & 7) * 96;                // 0..672

    const float* xr = x + ((long)b * Sc + s0 + r) * Dc + d0;
    float4 v[24];
    float s = 0.f, q = 0.f;
    #pragma unroll
    for (int i = 0; i < 24; i++) {
        v[i] = reinterpret_cast<const float4*>(xr)[i];
        s += v[i].x + v[i].y + v[i].z + v[i].w;
        q += v[i].x * v[i].x + v[i].y * v[i].y + v[i].z * v[i].z + v[i].w * v[i].w;
    }
    #pragma unroll
    for (int o = 1; o < 8; o <<= 1) { s += __shfl_xor(s, o); q += __shfl_xor(q, o); }
    const float mu   = s * (1.0f / Dc);
    const float var  = fmaxf(q * (1.0f / Dc) - mu * mu, 0.0f);
    const float rstd = 1.0f / sqrtf(var + 1e-5f);
    const float* ga = cln + (long)t * 2 * Dc + d0;
    const float* be = ga + Dc;
    #pragma unroll
    for (int i = 0; i < 24; i++) {
        const float4 g4 = reinterpret_cast<const float4*>(ga)[i];
        const float4 b4 = reinterpret_cast<const float4*>(be)[i];
        unsigned short* dst = &T[r * LDT + d0 + i * 4];
        __bf16 o0 = (__bf16)(g4.x * ((v[i].x - mu) * rstd) + b4.x);
        __bf16 o1 = (__bf16)(g4.y * ((v[i].y - mu) * rstd) + b4.y);
        __bf16 o2 = (__bf16)(g4.z * ((v[i].z - mu) * rstd) + b4.z);
        __bf16 o3 = (__bf16)(g4.w * ((v[i].w - mu) * rstd) + b4.w);
        dst[0] = __builtin_bit_cast(unsigned short, o0);
        dst[1] = __builtin_bit_cast(unsigned short, o1);
        dst[2] = __builtin_bit_cast(unsigned short, o2);
        dst[3] = __builtin_bit_cast(unsigned short, o3);
    }
    __syncthreads();
    #pragma unroll
    for (int c = 0; c < 3; c++) {
        const int d = tid + c * 256;
        unsigned short tmp[32];
        #pragma unroll
        for (int e = 0; e < 32; e++) tmp[e] = T[e * LDT + d];
        __bf16* dst = h1T + ((long)b * Dc + d) * Sc + s0;
        #pragma unroll
        for (int u = 0; u < 4; u++)
            reinterpret_cast<uint4*>(dst)[u] = reinterpret_cast<const uint4*>(tmp)[u];
    }
}

// ---------------- conditional LayerNorm, bf16 input -> bf16 ----------------
__global__ __launch_bounds__(192) void cond_ln_b(
    const __bf16* __restrict__ x, const int* __restrict__ tasks,
    const float* __restrict__ cln, __bf16* __restrict__ out)
{
    const int row = blockIdx.x;
    const int b   = row >> 10;
    const int t   = tasks[b];
    const int tid = threadIdx.x;
    const ushort4 u = reinterpret_cast<const ushort4*>(x + (long)row * Dc)[tid];
    const float v0 = bf2f(u.x), v1 = bf2f(u.y), v2 = bf2f(u.z), v3 = bf2f(u.w);
    float s = v0 + v1 + v2 + v3;
    float q = v0 * v0 + v1 * v1 + v2 * v2 + v3 * v3;
    #pragma unroll
    for (int o = 1; o < 64; o <<= 1) { s += __shfl_xor(s, o); q += __shfl_xor(q, o); }
    __shared__ float ss[3], qs[3];
    const int w = tid >> 6;
    if ((tid & 63) == 0) { ss[w] = s; qs[w] = q; }
    __syncthreads();
    s = ss[0] + ss[1] + ss[2];
    q = qs[0] + qs[1] + qs[2];
    const float mu   = s * (1.0f / Dc);
    const float var  = fmaxf(q * (1.0f / Dc) - mu * mu, 0.0f);
    const float rstd = 1.0f / sqrtf(var + 1e-5f);
    const float4 g  = reinterpret_cast<const float4*>(cln + (long)t * 2 * Dc)[tid];
    const float4 be = reinterpret_cast<const float4*>(cln + (long)t * 2 * Dc + Dc)[tid];
    bf16x4 o;
    o[0] = (__bf16)(g.x * ((v0 - mu) * rstd) + be.x);
    o[1] = (__bf16)(g.y * ((v1 - mu) * rstd) + be.y);
    o[2] = (__bf16)(g.z * ((v2 - mu) * rstd) + be.z);
    o[3] = (__bf16)(g.w * ((v3 - mu) * rstd) + be.w);
    *reinterpret_cast<bf16x4*>(out + (long)row * Dc + tid * 4) = o;
}

// ---------------- bf16 TN MFMA GEMM (round-2-proven inner loop) ------------
// C[b](MxN) = A(MxK, k-contig, lda) * B(NxK, k-contig, ldb)^T
// ATASK=1: A task-indexed, B batch-indexed; else A batch, B task.
// RESM: 0 none, 1 fp32 residual, 2 bf16 residual. OUTF32: fp32 vs bf16 out.
// launch_bounds(256,3): need ~140 unified regs < 512/3 cap -> no spill,
// 3 blocks/CU (12 waves). (256,4) spilled (round 4); (256,2) left BW on table.
template<int DOGELU, int RESM, int OUTF32, int ATASK>
__global__ __launch_bounds__(256, 3) void gemm_tn(
    const __bf16* __restrict__ A, long sA, int lda,
    const __bf16* __restrict__ B, long sB, int ldb,
    const void* __restrict__ R, long sR,
    void* __restrict__ C, long sC, int ldc,
    const int* __restrict__ tasks, int M, int N, int K)
{
    constexpr int BM = 128, BN = 128, BK = 64, LDP = 72;
    __shared__ unsigned short As[BM][LDP];
    __shared__ unsigned short Bs[BN][LDP];

    const int b = blockIdx.z;
    const int t = tasks[b];
    const __bf16* Ab = A + (ATASK ? (long)t : (long)b) * sA;
    const __bf16* Bb = B + (ATASK ? (long)b : (long)t) * sB;
    const int m0 = blockIdx.y * BM, n0 = blockIdx.x * BN;
    const int tid = threadIdx.x, lane = tid & 63, wid = tid >> 6;
    const int wm = (wid >> 1) * 64, wn = (wid & 1) * 64;
    const int l15 = lane & 15, l4 = lane >> 4;

    f32x4 acc[4][4];
    #pragma unroll
    for (int i = 0; i < 4; i++)
        #pragma unroll
        for (int j = 0; j < 4; j++)
            acc[i][j] = (f32x4){0.f, 0.f, 0.f, 0.f};

    for (int k0 = 0; k0 < K; k0 += BK) {
        #pragma unroll
        for (int rep = 0; rep < 4; rep++) {
            const int c = rep * 256 + tid;
            const int m = c >> 3, kc = (c & 7) * 8;
            const int gm = m0 + m, gk = k0 + kc;
            uint4 v = {0u, 0u, 0u, 0u};
            if (gm < M && gk < K)
                v = *reinterpret_cast<const uint4*>(Ab + (long)gm * lda + gk);
            *reinterpret_cast<uint4*>(&As[m][kc]) = v;
        }
        #pragma unroll
        for (int rep = 0; rep < 4; rep++) {
            const int c = rep * 256 + tid;
            const int n = c >> 3, kc = (c & 7) * 8;
            const int gk = k0 + kc, gn = n0 + n;
            uint4 v = {0u, 0u, 0u, 0u};
            if (gn < N && gk < K)
                v = *reinterpret_cast<const uint4*>(Bb + (long)gn * ldb + gk);
            *reinterpret_cast<uint4*>(&Bs[n][kc]) = v;
        }
        __syncthreads();
        #pragma unroll
        for (int h = 0; h < 2; h++) {
            bf16x8 af[4], bfr[4];
            #pragma unroll
            for (int i = 0; i < 4; i++)
                af[i] = *reinterpret_cast<const bf16x8*>(&As[wm + i * 16 + l15][h * 32 + l4 * 8]);
            #pragma unroll
            for (int j = 0; j < 4; j++)
                bfr[j] = *reinterpret_cast<const bf16x8*>(&Bs[wn + j * 16 + l15][h * 32 + l4 * 8]);
            #pragma unroll
            for (int i = 0; i < 4; i++)
                #pragma unroll
                for (int j = 0; j < 4; j++)
                    acc[i][j] = __builtin_amdgcn_mfma_f32_16x16x32_bf16(af[i], bfr[j], acc[i][j], 0, 0, 0);
        }
        __syncthreads();
    }

    float*  Cf = (float*)C  + (long)b * sC;
    __bf16* Ch = (__bf16*)C + (long)b * sC;
    const float*  Rf = (RESM == 1) ? ((const float*)R  + (long)b * sR) : nullptr;
    const __bf16* Rh = (RESM == 2) ? ((const __bf16*)R + (long)b * sR) : nullptr;

    #pragma unroll
    for (int i = 0; i < 4; i++) {
        #pragma unroll
        for (int j = 0; j < 4; j++) {
            const int gn = n0 + wn + j * 16 + l15;
            if (gn >= N) continue;
            #pragma unroll
            for (int r = 0; r < 4; r++) {
                const int gm = m0 + wm + i * 16 + l4 * 4 + r;
                if (gm >= M) continue;
                float v = acc[i][j][r];
                if (DOGELU) v = 0.5f * v * (1.0f + erff(v * 0.70710678118654752f));
                if (RESM == 1) v += Rf[(long)gm * ldc + gn];
                if (RESM == 2) v += (float)Rh[(long)gm * ldc + gn];
                if (OUTF32) Cf[(long)gm * ldc + gn] = v;
                else        Ch[(long)gm * ldc + gn] = (__bf16)v;
            }
        }
    }
}

extern "C" void kernel_launch(void* const* d_in, const int* in_sizes, int n_in,
                              void* d_out, int out_size, void* d_ws, size_t ws_size,
                              hipStream_t stream) {
    const float* x      = (const float*)d_in[0];
    const int*   tasks  = (const int*)  d_in[1];
    const float* cln1   = (const float*)d_in[2];
    const float* cln2   = (const float*)d_in[3];
    const float* w1_tok = (const float*)d_in[4];
    const float* w2_tok = (const float*)d_in[5];
    const float* w1_ch  = (const float*)d_in[6];
    const float* w2_ch  = (const float*)d_in[7];
    float* out = (float*)d_out;

    // ---- workspace layout (bytes) ----
    char* ws = (char*)d_ws;
    const long oT1 = 0;                               // wT1: 10 x ISp x Sc
    const long oT2 = oT1 + (long)10 * ISp * Sc * 2;   // wT2: 10 x Sc x ISp
    const long oC1 = oT2 + (long)10 * Sc * ISp * 2;   // wC1: 10 x IDp x Dc
    const long oC2 = oC1 + (long)10 * IDp * Dc * 2;   // wC2: 10 x Dc x IDp
    const long oA  = oC2 + (long)10 * Dc * IDp * 2;   // slabA: h1T then x1 (B*D*S bf16)
    const long oG  = oA  + (long)Bc * Dc * Sc * 2;    // gbf: GT / G2
    __bf16* wT1  = (__bf16*)(ws + oT1);
    __bf16* wT2  = (__bf16*)(ws + oT2);
    __bf16* wC1  = (__bf16*)(ws + oC1);
    __bf16* wC2  = (__bf16*)(ws + oC2);
    __bf16* h1T  = (__bf16*)(ws + oA);
    __bf16* x1   = (__bf16*)(ws + oA);                // reuses h1T (dead after GEMM2)
    __bf16* gbf  = (__bf16*)(ws + oG);
    __bf16* h2   = (__bf16*)d_out;                    // bf16 scratch inside d_out

    const dim3 blk(256);
    auto cdiv = [](long a, long b) { return (int)((a + b - 1) / b); };

    // 0) all weight conversions in one launch (task-major, zero-padded)
    cvt_all<<<cdiv(CB3, 256), blk, 0, stream>>>(
        w1_tok, w2_tok, w1_ch, w2_ch, wT1, wT2, wC1, wC2);

    // 1) h1T = condLN(x, cln1)^T   (B, D, S) bf16
    ln1_t<<<dim3(Sc / 32, Bc), blk, 0, stream>>>(x, tasks, cln1, h1T);

    // 2) GT = gelu(h1T @ W1tok[t]^T)   M=D, N=ISp, K=S
    gemm_tn<1, 0, 0, 0><<<dim3(cdiv(ISp, 128), Dc / 128, Bc), blk, 0, stream>>>(
        h1T, (long)Dc * Sc, Sc,
        wT1, (long)ISp * Sc, Sc,
        nullptr, 0,
        gbf, (long)Dc * ISp, ISp,
        tasks, Dc, ISp, Sc);

    // 3) x1 = x + W2tok[t] @ GT^T   M=S, N=D, K=ISp ; fp32 res; bf16 out
    gemm_tn<0, 1, 0, 1><<<dim3(Dc / 128, Sc / 128, Bc), blk, 0, stream>>>(
        wT2, (long)Sc * ISp, ISp,
        gbf, (long)Dc * ISp, ISp,
        x, (long)Sc * Dc,
        x1, (long)Sc * Dc, Dc,
        tasks, Sc, Dc, ISp);

    // 4) h2 = condLN(x1, cln2)  (bf16, in d_out scratch)
    cond_ln_b<<<Bc * Sc, 192, 0, stream>>>(x1, tasks, cln2, h2);

    // 5) G2 = gelu(h2 @ W1ch[t]^T)   M=S, N=IDp, K=D
    gemm_tn<1, 0, 0, 0><<<dim3(cdiv(IDp, 128), Sc / 128, Bc), blk, 0, stream>>>(
        h2, (long)Sc * Dc, Dc,
        wC1, (long)IDp * Dc, Dc,
        nullptr, 0,
        gbf, (long)Sc * IDp, IDp,
        tasks, Sc, IDp, Dc);

    // 6) out = x1 + G2 @ W2ch[t]^T   M=S, N=D, K=IDp ; bf16 res; fp32 out
    gemm_tn<0, 2, 1, 0><<<dim3(Dc / 128, Sc / 128, Bc), blk, 0, stream>>>(
        gbf, (long)Sc * IDp, IDp,
        wC2, (long)Dc * IDp, IDp,
        x1, (long)Sc * Dc,
        out, (long)Sc * Dc, Dc,
        tasks, Sc, Dc, IDp);
}

// Round 8
// 535.870 us; speedup vs baseline: 1.5356x; 1.5356x over previous
//
#include <hip/hip_runtime.h>
#include <math.h>

typedef __bf16 bf16x8 __attribute__((ext_vector_type(8)));
typedef __bf16 bf16x4 __attribute__((ext_vector_type(4)));
typedef float  f32x4  __attribute__((ext_vector_type(4)));

constexpr int Bc = 64, Sc = 1024, Dc = 768;
constexpr int ISc = 307, IDc = 230;
constexpr int ISp = 384, IDp = 256;   // padded so every GEMM M,N %128==0 and K %64==0

static __device__ __forceinline__ float bf2f(unsigned short u) {
    return __builtin_bit_cast(float, (unsigned)u << 16);
}

// async global->LDS, 16B per lane, linear LDS dest (wave-uniform base + lane*16)
static __device__ __forceinline__ void gload16(const void* g, void* l) {
    __builtin_amdgcn_global_load_lds(
        (const __attribute__((address_space(1))) void*)g,
        (__attribute__((address_space(3))) void*)l, 16, 0, 0);
}

// ---------------- fused fp32 -> bf16 weight convert (all 4 tensors) --------
constexpr int CH0 = 10 * ISp * (Sc  / 8);   // w1_tok -> wT1 (rows 307->384)
constexpr int CH1 = 10 * Sc  * (ISp / 8);   // w2_tok -> wT2 (cols 307->384)
constexpr int CH2 = 10 * IDp * (Dc  / 8);   // w1_ch  -> wC1 (rows 230->256)
constexpr int CH3 = 10 * Dc  * (IDp / 8);   // w2_ch  -> wC2 (cols 230->256)
constexpr int CB0 = CH0, CB1 = CB0 + CH1, CB2 = CB1 + CH2, CB3 = CB2 + CH3;

__device__ __forceinline__ void cvt_one(
    const float* __restrict__ in, __bf16* __restrict__ out,
    int inrows, int outrows, int incols, int outcols, int c)
{
    const int cpr  = outcols >> 3;
    const int perT = outrows * cpr;
    const int t    = c / perT;
    const int rem  = c - t * perT;
    const int r    = rem / cpr;
    const int cc   = (rem - r * cpr) * 8;
    bf16x8 o;
    if (r < inrows) {
        const float* src = in + ((long)t * inrows + r) * incols + cc;
        #pragma unroll
        for (int e = 0; e < 8; e++)
            o[e] = (cc + e < incols) ? (__bf16)src[e] : (__bf16)0.0f;
    } else {
        #pragma unroll
        for (int e = 0; e < 8; e++) o[e] = (__bf16)0.0f;
    }
    *reinterpret_cast<bf16x8*>(out + ((long)t * outrows + r) * outcols + cc) = o;
}

__global__ __launch_bounds__(256) void cvt_all(
    const float* __restrict__ w1t, const float* __restrict__ w2t,
    const float* __restrict__ w1c, const float* __restrict__ w2c,
    __bf16* __restrict__ o1t, __bf16* __restrict__ o2t,
    __bf16* __restrict__ o1c, __bf16* __restrict__ o2c)
{
    const int c = blockIdx.x * 256 + threadIdx.x;
    if (c < CB0)      cvt_one(w1t, o1t, ISc, ISp, Sc,  Sc,  c);
    else if (c < CB1) cvt_one(w2t, o2t, Sc,  Sc,  ISc, ISp, c - CB0);
    else if (c < CB2) cvt_one(w1c, o1c, IDc, IDp, Dc,  Dc,  c - CB1);
    else if (c < CB3) cvt_one(w2c, o2c, Dc,  Dc,  IDc, IDp, c - CB2);
}

// ---------------- LN1 fused with transpose: x (B,S,D) fp32 -> h1T (B,D,S) bf16
__global__ __launch_bounds__(256) void ln1_t(
    const float* __restrict__ x, const int* __restrict__ tasks,
    const float* __restrict__ cln, __bf16* __restrict__ h1T)
{
    constexpr int RPB = 32, LDT = Dc + 8;          // 776
    __shared__ unsigned short T[RPB * LDT];        // 48.5 KB
    const int b   = blockIdx.y;
    const int t   = tasks[b];
    const int s0  = blockIdx.x * RPB;
    const int tid = threadIdx.x;
    const int r   = tid >> 3;                      // 0..31
    const int d0  = (tid & 7) * 96;                // 0..672

    const float* xr = x + ((long)b * Sc + s0 + r) * Dc + d0;
    float4 v[24];
    float s = 0.f, q = 0.f;
    #pragma unroll
    for (int i = 0; i < 24; i++) {
        v[i] = reinterpret_cast<const float4*>(xr)[i];
        s += v[i].x + v[i].y + v[i].z + v[i].w;
        q += v[i].x * v[i].x + v[i].y * v[i].y + v[i].z * v[i].z + v[i].w * v[i].w;
    }
    #pragma unroll
    for (int o = 1; o < 8; o <<= 1) { s += __shfl_xor(s, o); q += __shfl_xor(q, o); }
    const float mu   = s * (1.0f / Dc);
    const float var  = fmaxf(q * (1.0f / Dc) - mu * mu, 0.0f);
    const float rstd = 1.0f / sqrtf(var + 1e-5f);
    const float* ga = cln + (long)t * 2 * Dc + d0;
    const float* be = ga + Dc;
    #pragma unroll
    for (int i = 0; i < 24; i++) {
        const float4 g4 = reinterpret_cast<const float4*>(ga)[i];
        const float4 b4 = reinterpret_cast<const float4*>(be)[i];
        unsigned short* dst = &T[r * LDT + d0 + i * 4];
        __bf16 o0 = (__bf16)(g4.x * ((v[i].x - mu) * rstd) + b4.x);
        __bf16 o1 = (__bf16)(g4.y * ((v[i].y - mu) * rstd) + b4.y);
        __bf16 o2 = (__bf16)(g4.z * ((v[i].z - mu) * rstd) + b4.z);
        __bf16 o3 = (__bf16)(g4.w * ((v[i].w - mu) * rstd) + b4.w);
        dst[0] = __builtin_bit_cast(unsigned short, o0);
        dst[1] = __builtin_bit_cast(unsigned short, o1);
        dst[2] = __builtin_bit_cast(unsigned short, o2);
        dst[3] = __builtin_bit_cast(unsigned short, o3);
    }
    __syncthreads();
    #pragma unroll
    for (int c = 0; c < 3; c++) {
        const int d = tid + c * 256;
        unsigned short tmp[32];
        #pragma unroll
        for (int e = 0; e < 32; e++) tmp[e] = T[e * LDT + d];
        __bf16* dst = h1T + ((long)b * Dc + d) * Sc + s0;
        #pragma unroll
        for (int u = 0; u < 4; u++)
            reinterpret_cast<uint4*>(dst)[u] = reinterpret_cast<const uint4*>(tmp)[u];
    }
}

// ---------------- conditional LayerNorm, bf16 input -> bf16 ----------------
__global__ __launch_bounds__(192) void cond_ln_b(
    const __bf16* __restrict__ x, const int* __restrict__ tasks,
    const float* __restrict__ cln, __bf16* __restrict__ out)
{
    const int row = blockIdx.x;
    const int b   = row >> 10;
    const int t   = tasks[b];
    const int tid = threadIdx.x;
    const ushort4 u = reinterpret_cast<const ushort4*>(x + (long)row * Dc)[tid];
    const float v0 = bf2f(u.x), v1 = bf2f(u.y), v2 = bf2f(u.z), v3 = bf2f(u.w);
    float s = v0 + v1 + v2 + v3;
    float q = v0 * v0 + v1 * v1 + v2 * v2 + v3 * v3;
    #pragma unroll
    for (int o = 1; o < 64; o <<= 1) { s += __shfl_xor(s, o); q += __shfl_xor(q, o); }
    __shared__ float ss[3], qs[3];
    const int w = tid >> 6;
    if ((tid & 63) == 0) { ss[w] = s; qs[w] = q; }
    __syncthreads();
    s = ss[0] + ss[1] + ss[2];
    q = qs[0] + qs[1] + qs[2];
    const float mu   = s * (1.0f / Dc);
    const float var  = fmaxf(q * (1.0f / Dc) - mu * mu, 0.0f);
    const float rstd = 1.0f / sqrtf(var + 1e-5f);
    const float4 g  = reinterpret_cast<const float4*>(cln + (long)t * 2 * Dc)[tid];
    const float4 be = reinterpret_cast<const float4*>(cln + (long)t * 2 * Dc + Dc)[tid];
    bf16x4 o;
    o[0] = (__bf16)(g.x * ((v0 - mu) * rstd) + be.x);
    o[1] = (__bf16)(g.y * ((v1 - mu) * rstd) + be.y);
    o[2] = (__bf16)(g.z * ((v2 - mu) * rstd) + be.z);
    o[3] = (__bf16)(g.w * ((v3 - mu) * rstd) + be.w);
    *reinterpret_cast<bf16x4*>(out + (long)row * Dc + tid * 4) = o;
}

// ---------------- bf16 TN MFMA GEMM, m97-style pipelined staging -----------
// C[b](MxN) = A(MxK,k-contig) * B(NxK,k-contig)^T.  ALL of M%128, N%128, K%64
// must be 0 (buffers pre-padded with zeros) -> staging has no guards.
// global_load_lds(16B) + double-buffered linear LDS; source k-chunk XOR-swizzled
// (chunk ^= row&7, involution) and the same XOR applied on ds_read (rule #21).
// STAGE(t+1) issues before compute(t); __syncthreads drains vmcnt+lgkm (m97).
template<int DOGELU, int RESM, int OUTF32, int ATASK>
__global__ __launch_bounds__(256, 2) void gemm_tn(
    const __bf16* __restrict__ A, long sA, int lda,
    const __bf16* __restrict__ B, long sB, int ldb,
    const void* __restrict__ R, long sR,
    void* __restrict__ C, long sC, int ldc,
    const int* __restrict__ tasks, int M, int N, int K)
{
    constexpr int BM = 128, BN = 128, BK = 64;
    constexpr int BUFB = 32768;                 // bytes per buffer: A 16K + B 16K
    __shared__ uint4 lds4[2 * BUFB / 16];       // 64 KB
    char* lbase = (char*)lds4;

    const int b = blockIdx.z;
    const int t = tasks[b];
    const __bf16* Ab = A + (ATASK ? (long)t : (long)b) * sA;
    const __bf16* Bb = B + (ATASK ? (long)b : (long)t) * sB;
    const int m0 = blockIdx.y * BM, n0 = blockIdx.x * BN;
    const int tid = threadIdx.x, lane = tid & 63, wid = tid >> 6;
    const int wm = (wid >> 1) * 64, wn = (wid & 1) * 64;
    const int l15 = lane & 15, l4 = lane >> 4;

    f32x4 acc[4][4];
    #pragma unroll
    for (int i = 0; i < 4; i++)
        #pragma unroll
        for (int j = 0; j < 4; j++)
            acc[i][j] = (f32x4){0.f, 0.f, 0.f, 0.f};

    auto STAGE = [&](int k0, int buf) {
        char* dst = lbase + buf * BUFB;
        #pragma unroll
        for (int rep = 0; rep < 4; rep++) {
            const int c = rep * 256 + tid;
            const int m = c >> 3, ch = c & 7;
            const int gk = k0 + ((ch ^ (m & 7)) << 3);
            gload16(Ab + (long)(m0 + m) * lda + gk, dst + c * 16);
        }
        #pragma unroll
        for (int rep = 0; rep < 4; rep++) {
            const int c = rep * 256 + tid;
            const int n = c >> 3, ch = c & 7;
            const int gk = k0 + ((ch ^ (n & 7)) << 3);
            gload16(Bb + (long)(n0 + n) * ldb + gk, dst + 16384 + c * 16);
        }
    };

    const int nt = K / BK;
    STAGE(0, 0);
    __syncthreads();
    int cur = 0;
    for (int tt = 0; tt < nt; tt++) {
        if (tt + 1 < nt) STAGE((tt + 1) * BK, cur ^ 1);
        const char* bb = lbase + cur * BUFB;
        #pragma unroll
        for (int h = 0; h < 2; h++) {
            bf16x8 af[4], bfr[4];
            #pragma unroll
            for (int i = 0; i < 4; i++) {
                const int row = wm + i * 16 + l15;
                af[i] = *reinterpret_cast<const bf16x8*>(
                    bb + row * 128 + (((h * 4 + l4) ^ (l15 & 7)) << 4));
            }
            #pragma unroll
            for (int j = 0; j < 4; j++) {
                const int row = wn + j * 16 + l15;
                bfr[j] = *reinterpret_cast<const bf16x8*>(
                    bb + 16384 + row * 128 + (((h * 4 + l4) ^ (l15 & 7)) << 4));
            }
            #pragma unroll
            for (int i = 0; i < 4; i++)
                #pragma unroll
                for (int j = 0; j < 4; j++)
                    acc[i][j] = __builtin_amdgcn_mfma_f32_16x16x32_bf16(af[i], bfr[j], acc[i][j], 0, 0, 0);
        }
        __syncthreads();
        cur ^= 1;
    }

    float*  Cf = (float*)C  + (long)b * sC;
    __bf16* Ch = (__bf16*)C + (long)b * sC;
    const float*  Rf = (RESM == 1) ? ((const float*)R  + (long)b * sR) : nullptr;
    const __bf16* Rh = (RESM == 2) ? ((const __bf16*)R + (long)b * sR) : nullptr;

    #pragma unroll
    for (int i = 0; i < 4; i++) {
        #pragma unroll
        for (int j = 0; j < 4; j++) {
            const int gn = n0 + wn + j * 16 + l15;
            #pragma unroll
            for (int r = 0; r < 4; r++) {
                const int gm = m0 + wm + i * 16 + l4 * 4 + r;
                float v = acc[i][j][r];
                if (DOGELU) v = 0.5f * v * (1.0f + erff(v * 0.70710678118654752f));
                if (RESM == 1) v += Rf[(long)gm * ldc + gn];
                if (RESM == 2) v += (float)Rh[(long)gm * ldc + gn];
                if (OUTF32) Cf[(long)gm * ldc + gn] = v;
                else        Ch[(long)gm * ldc + gn] = (__bf16)v;
            }
        }
    }
}

extern "C" void kernel_launch(void* const* d_in, const int* in_sizes, int n_in,
                              void* d_out, int out_size, void* d_ws, size_t ws_size,
                              hipStream_t stream) {
    const float* x      = (const float*)d_in[0];
    const int*   tasks  = (const int*)  d_in[1];
    const float* cln1   = (const float*)d_in[2];
    const float* cln2   = (const float*)d_in[3];
    const float* w1_tok = (const float*)d_in[4];
    const float* w2_tok = (const float*)d_in[5];
    const float* w1_ch  = (const float*)d_in[6];
    const float* w2_ch  = (const float*)d_in[7];
    float* out = (float*)d_out;

    // ---- workspace layout (bytes), ~162 MB ----
    char* ws = (char*)d_ws;
    const long oT1 = 0;                               // wT1: 10 x ISp x Sc
    const long oT2 = oT1 + (long)10 * ISp * Sc * 2;   // wT2: 10 x Sc x ISp
    const long oC1 = oT2 + (long)10 * Sc * ISp * 2;   // wC1: 10 x IDp x Dc
    const long oC2 = oC1 + (long)10 * IDp * Dc * 2;   // wC2: 10 x Dc x IDp
    const long oA  = oC2 + (long)10 * Dc * IDp * 2;   // slab: h1T then x1 (B*D*S bf16)
    const long oG  = oA  + (long)Bc * Dc * Sc * 2;    // gbf: max(B*D*ISp, B*S*IDp) bf16
    __bf16* wT1  = (__bf16*)(ws + oT1);
    __bf16* wT2  = (__bf16*)(ws + oT2);
    __bf16* wC1  = (__bf16*)(ws + oC1);
    __bf16* wC2  = (__bf16*)(ws + oC2);
    __bf16* h1T  = (__bf16*)(ws + oA);
    __bf16* x1   = (__bf16*)(ws + oA);                // reuses h1T (dead after GEMM2)
    __bf16* gbf  = (__bf16*)(ws + oG);
    __bf16* h2   = (__bf16*)d_out;                    // bf16 scratch inside d_out

    const dim3 blk(256);
    auto cdiv = [](long a, long b) { return (int)((a + b - 1) / b); };

    // 0) all weight conversions in one launch (task-major, zero-padded)
    cvt_all<<<cdiv(CB3, 256), blk, 0, stream>>>(
        w1_tok, w2_tok, w1_ch, w2_ch, wT1, wT2, wC1, wC2);

    // 1) h1T = condLN(x, cln1)^T   (B, D, S) bf16
    ln1_t<<<dim3(Sc / 32, Bc), blk, 0, stream>>>(x, tasks, cln1, h1T);

    // 2) GT = gelu(h1T @ W1tok[t]^T)   M=768, N=384, K=1024
    gemm_tn<1, 0, 0, 0><<<dim3(ISp / 128, Dc / 128, Bc), blk, 0, stream>>>(
        h1T, (long)Dc * Sc, Sc,
        wT1, (long)ISp * Sc, Sc,
        nullptr, 0,
        gbf, (long)Dc * ISp, ISp,
        tasks, Dc, ISp, Sc);

    // 3) x1 = x + W2tok[t] @ GT^T   M=1024, N=768, K=384 ; fp32 res; bf16 out
    gemm_tn<0, 1, 0, 1><<<dim3(Dc / 128, Sc / 128, Bc), blk, 0, stream>>>(
        wT2, (long)Sc * ISp, ISp,
        gbf, (long)Dc * ISp, ISp,
        x, (long)Sc * Dc,
        x1, (long)Sc * Dc, Dc,
        tasks, Sc, Dc, ISp);

    // 4) h2 = condLN(x1, cln2)  (bf16, in d_out scratch)
    cond_ln_b<<<Bc * Sc, 192, 0, stream>>>(x1, tasks, cln2, h2);

    // 5) G2 = gelu(h2 @ W1ch[t]^T)   M=1024, N=256, K=768
    gemm_tn<1, 0, 0, 0><<<dim3(IDp / 128, Sc / 128, Bc), blk, 0, stream>>>(
        h2, (long)Sc * Dc, Dc,
        wC1, (long)IDp * Dc, Dc,
        nullptr, 0,
        gbf, (long)Sc * IDp, IDp,
        tasks, Sc, IDp, Dc);

    // 6) out = x1 + G2 @ W2ch[t]^T   M=1024, N=768, K=256 ; bf16 res; fp32 out
    gemm_tn<0, 2, 1, 0><<<dim3(Dc / 128, Sc / 128, Bc), blk, 0, stream>>>(
        gbf, (long)Sc * IDp, IDp,
        wC2, (long)Dc * IDp, IDp,
        x1, (long)Sc * Dc,
        out, (long)Sc * Dc, Dc,
        tasks, Sc, Dc, IDp);
}

// Round 9
// 492.260 us; speedup vs baseline: 1.6716x; 1.0886x over previous
//
#include <hip/hip_runtime.h>
#include <math.h>

typedef __bf16 bf16x8 __attribute__((ext_vector_type(8)));
typedef __bf16 bf16x4 __attribute__((ext_vector_type(4)));
typedef float  f32x4  __attribute__((ext_vector_type(4)));

constexpr int Bc = 64, Sc = 1024, Dc = 768;
constexpr int ISc = 307, IDc = 230;
constexpr int ISp = 384, IDp = 256;   // padded so every GEMM M,N %128==0 and K %64==0

static __device__ __forceinline__ float bf2f(unsigned short u) {
    return __builtin_bit_cast(float, (unsigned)u << 16);
}

// async global->LDS, 16B per lane, linear LDS dest (wave-uniform base + lane*16)
static __device__ __forceinline__ void gload16(const void* g, void* l) {
    __builtin_amdgcn_global_load_lds(
        (const __attribute__((address_space(1))) void*)g,
        (__attribute__((address_space(3))) void*)l, 16, 0, 0);
}

// ---------------- fused fp32 -> bf16 weight convert (all 4 tensors) --------
constexpr int CH0 = 10 * ISp * (Sc  / 8);   // w1_tok -> wT1 (rows 307->384)
constexpr int CH1 = 10 * Sc  * (ISp / 8);   // w2_tok -> wT2 (cols 307->384)
constexpr int CH2 = 10 * IDp * (Dc  / 8);   // w1_ch  -> wC1 (rows 230->256)
constexpr int CH3 = 10 * Dc  * (IDp / 8);   // w2_ch  -> wC2 (cols 230->256)
constexpr int CB0 = CH0, CB1 = CB0 + CH1, CB2 = CB1 + CH2, CB3 = CB2 + CH3;

__device__ __forceinline__ void cvt_one(
    const float* __restrict__ in, __bf16* __restrict__ out,
    int inrows, int outrows, int incols, int outcols, int c)
{
    const int cpr  = outcols >> 3;
    const int perT = outrows * cpr;
    const int t    = c / perT;
    const int rem  = c - t * perT;
    const int r    = rem / cpr;
    const int cc   = (rem - r * cpr) * 8;
    bf16x8 o;
    if (r < inrows) {
        const float* src = in + ((long)t * inrows + r) * incols + cc;
        #pragma unroll
        for (int e = 0; e < 8; e++)
            o[e] = (cc + e < incols) ? (__bf16)src[e] : (__bf16)0.0f;
    } else {
        #pragma unroll
        for (int e = 0; e < 8; e++) o[e] = (__bf16)0.0f;
    }
    *reinterpret_cast<bf16x8*>(out + ((long)t * outrows + r) * outcols + cc) = o;
}

__global__ __launch_bounds__(256) void cvt_all(
    const float* __restrict__ w1t, const float* __restrict__ w2t,
    const float* __restrict__ w1c, const float* __restrict__ w2c,
    __bf16* __restrict__ o1t, __bf16* __restrict__ o2t,
    __bf16* __restrict__ o1c, __bf16* __restrict__ o2c)
{
    const int c = blockIdx.x * 256 + threadIdx.x;
    if (c < CB0)      cvt_one(w1t, o1t, ISc, ISp, Sc,  Sc,  c);
    else if (c < CB1) cvt_one(w2t, o2t, Sc,  Sc,  ISc, ISp, c - CB0);
    else if (c < CB2) cvt_one(w1c, o1c, IDc, IDp, Dc,  Dc,  c - CB1);
    else if (c < CB3) cvt_one(w2c, o2c, Dc,  Dc,  IDc, IDp, c - CB2);
}

// ---------------- LN1 fused with transpose: x (B,S,D) fp32 -> h1T (B,D,S) bf16
// wave-per-row phase 1 (coalesced float4 lane-stride reads), padded-LDS
// transpose, phase-2 write-out 64B/lane (proven in r8).
__global__ __launch_bounds__(256) void ln1_t(
    const float* __restrict__ x, const int* __restrict__ tasks,
    const float* __restrict__ cln, __bf16* __restrict__ h1T)
{
    constexpr int RPB = 32, LDT = Dc + 8;          // 776 shorts/row
    __shared__ unsigned short T[RPB * LDT];        // 48.5 KB
    const int b   = blockIdx.y;
    const int t   = tasks[b];
    const int s0  = blockIdx.x * RPB;
    const int tid = threadIdx.x;
    const int wv  = tid >> 6;                      // wave 0..3
    const int l   = tid & 63;

    // hoisted gamma/beta (12 float4 each lane covers via 3 slots x4)
    const float4* Ga = reinterpret_cast<const float4*>(cln + (long)t * 2 * Dc);
    const float4* Be = reinterpret_cast<const float4*>(cln + (long)t * 2 * Dc + Dc);
    const float4 g0 = Ga[l], g1 = Ga[l + 64], g2 = Ga[l + 128];
    const float4 b0 = Be[l], b1 = Be[l + 64], b2 = Be[l + 128];

    #pragma unroll
    for (int rr = 0; rr < 8; rr++) {
        const int r = wv * 8 + rr;
        const float4* xr = reinterpret_cast<const float4*>(x + ((long)b * Sc + s0 + r) * Dc);
        const float4 v0 = xr[l], v1 = xr[l + 64], v2 = xr[l + 128];
        float s = v0.x + v0.y + v0.z + v0.w + v1.x + v1.y + v1.z + v1.w
                + v2.x + v2.y + v2.z + v2.w;
        float q = v0.x*v0.x + v0.y*v0.y + v0.z*v0.z + v0.w*v0.w
                + v1.x*v1.x + v1.y*v1.y + v1.z*v1.z + v1.w*v1.w
                + v2.x*v2.x + v2.y*v2.y + v2.z*v2.z + v2.w*v2.w;
        #pragma unroll
        for (int o = 1; o < 64; o <<= 1) { s += __shfl_xor(s, o); q += __shfl_xor(q, o); }
        const float mu   = s * (1.0f / Dc);
        const float var  = fmaxf(q * (1.0f / Dc) - mu * mu, 0.0f);
        const float rstd = 1.0f / sqrtf(var + 1e-5f);
        unsigned short* tr = &T[r * LDT];
        bf16x4 o0, o1, o2;
        o0[0] = (__bf16)(g0.x * ((v0.x - mu) * rstd) + b0.x);
        o0[1] = (__bf16)(g0.y * ((v0.y - mu) * rstd) + b0.y);
        o0[2] = (__bf16)(g0.z * ((v0.z - mu) * rstd) + b0.z);
        o0[3] = (__bf16)(g0.w * ((v0.w - mu) * rstd) + b0.w);
        o1[0] = (__bf16)(g1.x * ((v1.x - mu) * rstd) + b1.x);
        o1[1] = (__bf16)(g1.y * ((v1.y - mu) * rstd) + b1.y);
        o1[2] = (__bf16)(g1.z * ((v1.z - mu) * rstd) + b1.z);
        o1[3] = (__bf16)(g1.w * ((v1.w - mu) * rstd) + b1.w);
        o2[0] = (__bf16)(g2.x * ((v2.x - mu) * rstd) + b2.x);
        o2[1] = (__bf16)(g2.y * ((v2.y - mu) * rstd) + b2.y);
        o2[2] = (__bf16)(g2.z * ((v2.z - mu) * rstd) + b2.z);
        o2[3] = (__bf16)(g2.w * ((v2.w - mu) * rstd) + b2.w);
        *reinterpret_cast<bf16x4*>(&tr[l * 4])        = o0;
        *reinterpret_cast<bf16x4*>(&tr[256 + l * 4])  = o1;
        *reinterpret_cast<bf16x4*>(&tr[512 + l * 4])  = o2;
    }
    __syncthreads();
    #pragma unroll
    for (int c = 0; c < 3; c++) {
        const int d = tid + c * 256;
        unsigned short tmp[32];
        #pragma unroll
        for (int e = 0; e < 32; e++) tmp[e] = T[e * LDT + d];
        __bf16* dst = h1T + ((long)b * Dc + d) * Sc + s0;
        #pragma unroll
        for (int u = 0; u < 4; u++)
            reinterpret_cast<uint4*>(dst)[u] = reinterpret_cast<const uint4*>(tmp)[u];
    }
}

// ---------------- conditional LayerNorm, bf16 -> bf16, wave-per-row --------
__global__ __launch_bounds__(256) void cond_ln_b(
    const __bf16* __restrict__ x, const int* __restrict__ tasks,
    const float* __restrict__ cln, __bf16* __restrict__ out)
{
    const int row = blockIdx.x * 4 + (threadIdx.x >> 6);   // 4 rows/block
    const int b   = row >> 10;
    const int t   = tasks[b];
    const int l   = threadIdx.x & 63;
    const ushort4* xr = reinterpret_cast<const ushort4*>(x + (long)row * Dc);
    const ushort4 u0 = xr[l], u1 = xr[l + 64], u2 = xr[l + 128];
    float v[12];
    v[0]=bf2f(u0.x); v[1]=bf2f(u0.y); v[2]=bf2f(u0.z); v[3]=bf2f(u0.w);
    v[4]=bf2f(u1.x); v[5]=bf2f(u1.y); v[6]=bf2f(u1.z); v[7]=bf2f(u1.w);
    v[8]=bf2f(u2.x); v[9]=bf2f(u2.y); v[10]=bf2f(u2.z); v[11]=bf2f(u2.w);
    float s = 0.f, q = 0.f;
    #pragma unroll
    for (int e = 0; e < 12; e++) { s += v[e]; q += v[e] * v[e]; }
    #pragma unroll
    for (int o = 1; o < 64; o <<= 1) { s += __shfl_xor(s, o); q += __shfl_xor(q, o); }
    const float mu   = s * (1.0f / Dc);
    const float var  = fmaxf(q * (1.0f / Dc) - mu * mu, 0.0f);
    const float rstd = 1.0f / sqrtf(var + 1e-5f);
    const float4* Ga = reinterpret_cast<const float4*>(cln + (long)t * 2 * Dc);
    const float4* Be = reinterpret_cast<const float4*>(cln + (long)t * 2 * Dc + Dc);
    ushort4* orow = reinterpret_cast<ushort4*>(out + (long)row * Dc);
    #pragma unroll
    for (int c = 0; c < 3; c++) {
        const float4 g = Ga[l + c * 64], be = Be[l + c * 64];
        bf16x4 o;
        o[0] = (__bf16)(g.x * ((v[c*4+0] - mu) * rstd) + be.x);
        o[1] = (__bf16)(g.y * ((v[c*4+1] - mu) * rstd) + be.y);
        o[2] = (__bf16)(g.z * ((v[c*4+2] - mu) * rstd) + be.z);
        o[3] = (__bf16)(g.w * ((v[c*4+3] - mu) * rstd) + be.w);
        orow[l + c * 64] = __builtin_bit_cast(ushort4, o);
    }
}

// ---------------- bf16 TN MFMA GEMM, m97-style pipelined staging -----------
// (unchanged from round 8 — proven at <131 us/dispatch)
template<int DOGELU, int RESM, int OUTF32, int ATASK>
__global__ __launch_bounds__(256, 2) void gemm_tn(
    const __bf16* __restrict__ A, long sA, int lda,
    const __bf16* __restrict__ B, long sB, int ldb,
    const void* __restrict__ R, long sR,
    void* __restrict__ C, long sC, int ldc,
    const int* __restrict__ tasks, int M, int N, int K)
{
    constexpr int BM = 128, BN = 128, BK = 64;
    constexpr int BUFB = 32768;                 // bytes per buffer: A 16K + B 16K
    __shared__ uint4 lds4[2 * BUFB / 16];       // 64 KB
    char* lbase = (char*)lds4;

    const int b = blockIdx.z;
    const int t = tasks[b];
    const __bf16* Ab = A + (ATASK ? (long)t : (long)b) * sA;
    const __bf16* Bb = B + (ATASK ? (long)b : (long)t) * sB;
    const int m0 = blockIdx.y * BM, n0 = blockIdx.x * BN;
    const int tid = threadIdx.x, lane = tid & 63, wid = tid >> 6;
    const int wm = (wid >> 1) * 64, wn = (wid & 1) * 64;
    const int l15 = lane & 15, l4 = lane >> 4;

    f32x4 acc[4][4];
    #pragma unroll
    for (int i = 0; i < 4; i++)
        #pragma unroll
        for (int j = 0; j < 4; j++)
            acc[i][j] = (f32x4){0.f, 0.f, 0.f, 0.f};

    auto STAGE = [&](int k0, int buf) {
        char* dst = lbase + buf * BUFB;
        #pragma unroll
        for (int rep = 0; rep < 4; rep++) {
            const int c = rep * 256 + tid;
            const int m = c >> 3, ch = c & 7;
            const int gk = k0 + ((ch ^ (m & 7)) << 3);
            gload16(Ab + (long)(m0 + m) * lda + gk, dst + c * 16);
        }
        #pragma unroll
        for (int rep = 0; rep < 4; rep++) {
            const int c = rep * 256 + tid;
            const int n = c >> 3, ch = c & 7;
            const int gk = k0 + ((ch ^ (n & 7)) << 3);
            gload16(Bb + (long)(n0 + n) * ldb + gk, dst + 16384 + c * 16);
        }
    };

    const int nt = K / BK;
    STAGE(0, 0);
    __syncthreads();
    int cur = 0;
    for (int tt = 0; tt < nt; tt++) {
        if (tt + 1 < nt) STAGE((tt + 1) * BK, cur ^ 1);
        const char* bb = lbase + cur * BUFB;
        #pragma unroll
        for (int h = 0; h < 2; h++) {
            bf16x8 af[4], bfr[4];
            #pragma unroll
            for (int i = 0; i < 4; i++) {
                const int row = wm + i * 16 + l15;
                af[i] = *reinterpret_cast<const bf16x8*>(
                    bb + row * 128 + (((h * 4 + l4) ^ (l15 & 7)) << 4));
            }
            #pragma unroll
            for (int j = 0; j < 4; j++) {
                const int row = wn + j * 16 + l15;
                bfr[j] = *reinterpret_cast<const bf16x8*>(
                    bb + 16384 + row * 128 + (((h * 4 + l4) ^ (l15 & 7)) << 4));
            }
            #pragma unroll
            for (int i = 0; i < 4; i++)
                #pragma unroll
                for (int j = 0; j < 4; j++)
                    acc[i][j] = __builtin_amdgcn_mfma_f32_16x16x32_bf16(af[i], bfr[j], acc[i][j], 0, 0, 0);
        }
        __syncthreads();
        cur ^= 1;
    }

    float*  Cf = (float*)C  + (long)b * sC;
    __bf16* Ch = (__bf16*)C + (long)b * sC;
    const float*  Rf = (RESM == 1) ? ((const float*)R  + (long)b * sR) : nullptr;
    const __bf16* Rh = (RESM == 2) ? ((const __bf16*)R + (long)b * sR) : nullptr;

    #pragma unroll
    for (int i = 0; i < 4; i++) {
        #pragma unroll
        for (int j = 0; j < 4; j++) {
            const int gn = n0 + wn + j * 16 + l15;
            #pragma unroll
            for (int r = 0; r < 4; r++) {
                const int gm = m0 + wm + i * 16 + l4 * 4 + r;
                float v = acc[i][j][r];
                if (DOGELU) v = 0.5f * v * (1.0f + erff(v * 0.70710678118654752f));
                if (RESM == 1) v += Rf[(long)gm * ldc + gn];
                if (RESM == 2) v += (float)Rh[(long)gm * ldc + gn];
                if (OUTF32) Cf[(long)gm * ldc + gn] = v;
                else        Ch[(long)gm * ldc + gn] = (__bf16)v;
            }
        }
    }
}

extern "C" void kernel_launch(void* const* d_in, const int* in_sizes, int n_in,
                              void* d_out, int out_size, void* d_ws, size_t ws_size,
                              hipStream_t stream) {
    const float* x      = (const float*)d_in[0];
    const int*   tasks  = (const int*)  d_in[1];
    const float* cln1   = (const float*)d_in[2];
    const float* cln2   = (const float*)d_in[3];
    const float* w1_tok = (const float*)d_in[4];
    const float* w2_tok = (const float*)d_in[5];
    const float* w1_ch  = (const float*)d_in[6];
    const float* w2_ch  = (const float*)d_in[7];
    float* out = (float*)d_out;

    // ---- workspace layout (bytes) ----
    char* ws = (char*)d_ws;
    const long oT1 = 0;                               // wT1: 10 x ISp x Sc
    const long oT2 = oT1 + (long)10 * ISp * Sc * 2;   // wT2: 10 x Sc x ISp
    const long oC1 = oT2 + (long)10 * Sc * ISp * 2;   // wC1: 10 x IDp x Dc
    const long oC2 = oC1 + (long)10 * IDp * Dc * 2;   // wC2: 10 x Dc x IDp
    const long oA  = oC2 + (long)10 * Dc * IDp * 2;   // slab: h1T then x1 (B*D*S bf16)
    const long oG  = oA  + (long)Bc * Dc * Sc * 2;    // gbf
    __bf16* wT1  = (__bf16*)(ws + oT1);
    __bf16* wT2  = (__bf16*)(ws + oT2);
    __bf16* wC1  = (__bf16*)(ws + oC1);
    __bf16* wC2  = (__bf16*)(ws + oC2);
    __bf16* h1T  = (__bf16*)(ws + oA);
    __bf16* x1   = (__bf16*)(ws + oA);                // reuses h1T (dead after GEMM2)
    __bf16* gbf  = (__bf16*)(ws + oG);
    __bf16* h2   = (__bf16*)d_out;                    // bf16 scratch inside d_out

    const dim3 blk(256);
    auto cdiv = [](long a, long b) { return (int)((a + b - 1) / b); };

    // 0) all weight conversions in one launch (task-major, zero-padded)
    cvt_all<<<cdiv(CB3, 256), blk, 0, stream>>>(
        w1_tok, w2_tok, w1_ch, w2_ch, wT1, wT2, wC1, wC2);

    // 1) h1T = condLN(x, cln1)^T   (B, D, S) bf16
    ln1_t<<<dim3(Sc / 32, Bc), blk, 0, stream>>>(x, tasks, cln1, h1T);

    // 2) GT = gelu(h1T @ W1tok[t]^T)   M=768, N=384, K=1024
    gemm_tn<1, 0, 0, 0><<<dim3(ISp / 128, Dc / 128, Bc), blk, 0, stream>>>(
        h1T, (long)Dc * Sc, Sc,
        wT1, (long)ISp * Sc, Sc,
        nullptr, 0,
        gbf, (long)Dc * ISp, ISp,
        tasks, Dc, ISp, Sc);

    // 3) x1 = x + W2tok[t] @ GT^T   M=1024, N=768, K=384 ; fp32 res; bf16 out
    gemm_tn<0, 1, 0, 1><<<dim3(Dc / 128, Sc / 128, Bc), blk, 0, stream>>>(
        wT2, (long)Sc * ISp, ISp,
        gbf, (long)Dc * ISp, ISp,
        x, (long)Sc * Dc,
        x1, (long)Sc * Dc, Dc,
        tasks, Sc, Dc, ISp);

    // 4) h2 = condLN(x1, cln2)  (bf16, in d_out scratch)
    cond_ln_b<<<(Bc * Sc) / 4, blk, 0, stream>>>(x1, tasks, cln2, h2);

    // 5) G2 = gelu(h2 @ W1ch[t]^T)   M=1024, N=256, K=768
    gemm_tn<1, 0, 0, 0><<<dim3(IDp / 128, Sc / 128, Bc), blk, 0, stream>>>(
        h2, (long)Sc * Dc, Dc,
        wC1, (long)IDp * Dc, Dc,
        nullptr, 0,
        gbf, (long)Sc * IDp, IDp,
        tasks, Sc, IDp, Dc);

    // 6) out = x1 + G2 @ W2ch[t]^T   M=1024, N=768, K=256 ; bf16 res; fp32 out
    gemm_tn<0, 2, 1, 0><<<dim3(Dc / 128, Sc / 128, Bc), blk, 0, stream>>>(
        gbf, (long)Sc * IDp, IDp,
        wC2, (long)Dc * IDp, IDp,
        x1, (long)Sc * Dc,
        out, (long)Sc * Dc, Dc,
        tasks, Sc, Dc, IDp);
}

// Round 10
// 491.988 us; speedup vs baseline: 1.6725x; 1.0006x over previous
//
#include <hip/hip_runtime.h>
#include <math.h>

typedef __bf16 bf16x8 __attribute__((ext_vector_type(8)));
typedef __bf16 bf16x4 __attribute__((ext_vector_type(4)));
typedef float  f32x4  __attribute__((ext_vector_type(4)));

constexpr int Bc = 64, Sc = 1024, Dc = 768;
constexpr int ISc = 307, IDc = 230;
constexpr int ISp = 384, IDp = 256;   // padded so every GEMM M,N %128==0 and K %64==0

static __device__ __forceinline__ float bf2f(unsigned short u) {
    return __builtin_bit_cast(float, (unsigned)u << 16);
}

// async global->LDS, 16B per lane, linear LDS dest (wave-uniform base + lane*16)
static __device__ __forceinline__ void gload16(const void* g, void* l) {
    __builtin_amdgcn_global_load_lds(
        (const __attribute__((address_space(1))) void*)g,
        (__attribute__((address_space(3))) void*)l, 16, 0, 0);
}

// ---------------- fused fp32 -> bf16 weight convert (all 4 tensors) --------
constexpr int CH0 = 10 * ISp * (Sc  / 8);   // w1_tok -> wT1 (rows 307->384)
constexpr int CH1 = 10 * Sc  * (ISp / 8);   // w2_tok -> wT2 (cols 307->384)
constexpr int CH2 = 10 * IDp * (Dc  / 8);   // w1_ch  -> wC1 (rows 230->256)
constexpr int CH3 = 10 * Dc  * (IDp / 8);   // w2_ch  -> wC2 (cols 230->256)
constexpr int CB0 = CH0, CB1 = CB0 + CH1, CB2 = CB1 + CH2, CB3 = CB2 + CH3;

__device__ __forceinline__ void cvt_one(
    const float* __restrict__ in, __bf16* __restrict__ out,
    int inrows, int outrows, int incols, int outcols, int c)
{
    const int cpr  = outcols >> 3;
    const int perT = outrows * cpr;
    const int t    = c / perT;
    const int rem  = c - t * perT;
    const int r    = rem / cpr;
    const int cc   = (rem - r * cpr) * 8;
    bf16x8 o;
    if (r < inrows) {
        const float* src = in + ((long)t * inrows + r) * incols + cc;
        #pragma unroll
        for (int e = 0; e < 8; e++)
            o[e] = (cc + e < incols) ? (__bf16)src[e] : (__bf16)0.0f;
    } else {
        #pragma unroll
        for (int e = 0; e < 8; e++) o[e] = (__bf16)0.0f;
    }
    *reinterpret_cast<bf16x8*>(out + ((long)t * outrows + r) * outcols + cc) = o;
}

__global__ __launch_bounds__(256) void cvt_all(
    const float* __restrict__ w1t, const float* __restrict__ w2t,
    const float* __restrict__ w1c, const float* __restrict__ w2c,
    __bf16* __restrict__ o1t, __bf16* __restrict__ o2t,
    __bf16* __restrict__ o1c, __bf16* __restrict__ o2c)
{
    const int c = blockIdx.x * 256 + threadIdx.x;
    if (c < CB0)      cvt_one(w1t, o1t, ISc, ISp, Sc,  Sc,  c);
    else if (c < CB1) cvt_one(w2t, o2t, Sc,  Sc,  ISc, ISp, c - CB0);
    else if (c < CB2) cvt_one(w1c, o1c, IDc, IDp, Dc,  Dc,  c - CB1);
    else if (c < CB3) cvt_one(w2c, o2c, Dc,  Dc,  IDc, IDp, c - CB2);
}

// ---------------- LN1 fused with transpose: x (B,S,D) fp32 -> h1T (B,D,S) bf16
// wave-per-row phase 1 (coalesced float4 lane-stride reads), padded-LDS
// transpose, phase-2 write-out 64B/lane (proven in r8).
__global__ __launch_bounds__(256) void ln1_t(
    const float* __restrict__ x, const int* __restrict__ tasks,
    const float* __restrict__ cln, __bf16* __restrict__ h1T)
{
    constexpr int RPB = 32, LDT = Dc + 8;          // 776 shorts/row
    __shared__ unsigned short T[RPB * LDT];        // 48.5 KB
    const int b   = blockIdx.y;
    const int t   = tasks[b];
    const int s0  = blockIdx.x * RPB;
    const int tid = threadIdx.x;
    const int wv  = tid >> 6;                      // wave 0..3
    const int l   = tid & 63;

    // hoisted gamma/beta (12 float4 each lane covers via 3 slots x4)
    const float4* Ga = reinterpret_cast<const float4*>(cln + (long)t * 2 * Dc);
    const float4* Be = reinterpret_cast<const float4*>(cln + (long)t * 2 * Dc + Dc);
    const float4 g0 = Ga[l], g1 = Ga[l + 64], g2 = Ga[l + 128];
    const float4 b0 = Be[l], b1 = Be[l + 64], b2 = Be[l + 128];

    #pragma unroll
    for (int rr = 0; rr < 8; rr++) {
        const int r = wv * 8 + rr;
        const float4* xr = reinterpret_cast<const float4*>(x + ((long)b * Sc + s0 + r) * Dc);
        const float4 v0 = xr[l], v1 = xr[l + 64], v2 = xr[l + 128];
        float s = v0.x + v0.y + v0.z + v0.w + v1.x + v1.y + v1.z + v1.w
                + v2.x + v2.y + v2.z + v2.w;
        float q = v0.x*v0.x + v0.y*v0.y + v0.z*v0.z + v0.w*v0.w
                + v1.x*v1.x + v1.y*v1.y + v1.z*v1.z + v1.w*v1.w
                + v2.x*v2.x + v2.y*v2.y + v2.z*v2.z + v2.w*v2.w;
        #pragma unroll
        for (int o = 1; o < 64; o <<= 1) { s += __shfl_xor(s, o); q += __shfl_xor(q, o); }
        const float mu   = s * (1.0f / Dc);
        const float var  = fmaxf(q * (1.0f / Dc) - mu * mu, 0.0f);
        const float rstd = 1.0f / sqrtf(var + 1e-5f);
        unsigned short* tr = &T[r * LDT];
        bf16x4 o0, o1, o2;
        o0[0] = (__bf16)(g0.x * ((v0.x - mu) * rstd) + b0.x);
        o0[1] = (__bf16)(g0.y * ((v0.y - mu) * rstd) + b0.y);
        o0[2] = (__bf16)(g0.z * ((v0.z - mu) * rstd) + b0.z);
        o0[3] = (__bf16)(g0.w * ((v0.w - mu) * rstd) + b0.w);
        o1[0] = (__bf16)(g1.x * ((v1.x - mu) * rstd) + b1.x);
        o1[1] = (__bf16)(g1.y * ((v1.y - mu) * rstd) + b1.y);
        o1[2] = (__bf16)(g1.z * ((v1.z - mu) * rstd) + b1.z);
        o1[3] = (__bf16)(g1.w * ((v1.w - mu) * rstd) + b1.w);
        o2[0] = (__bf16)(g2.x * ((v2.x - mu) * rstd) + b2.x);
        o2[1] = (__bf16)(g2.y * ((v2.y - mu) * rstd) + b2.y);
        o2[2] = (__bf16)(g2.z * ((v2.z - mu) * rstd) + b2.z);
        o2[3] = (__bf16)(g2.w * ((v2.w - mu) * rstd) + b2.w);
        *reinterpret_cast<bf16x4*>(&tr[l * 4])        = o0;
        *reinterpret_cast<bf16x4*>(&tr[256 + l * 4])  = o1;
        *reinterpret_cast<bf16x4*>(&tr[512 + l * 4])  = o2;
    }
    __syncthreads();
    #pragma unroll
    for (int c = 0; c < 3; c++) {
        const int d = tid + c * 256;
        unsigned short tmp[32];
        #pragma unroll
        for (int e = 0; e < 32; e++) tmp[e] = T[e * LDT + d];
        __bf16* dst = h1T + ((long)b * Dc + d) * Sc + s0;
        #pragma unroll
        for (int u = 0; u < 4; u++)
            reinterpret_cast<uint4*>(dst)[u] = reinterpret_cast<const uint4*>(tmp)[u];
    }
}

// ---------------- conditional LayerNorm, bf16 -> bf16, wave-per-row --------
__global__ __launch_bounds__(256) void cond_ln_b(
    const __bf16* __restrict__ x, const int* __restrict__ tasks,
    const float* __restrict__ cln, __bf16* __restrict__ out)
{
    const int row = blockIdx.x * 4 + (threadIdx.x >> 6);   // 4 rows/block
    const int b   = row >> 10;
    const int t   = tasks[b];
    const int l   = threadIdx.x & 63;
    const ushort4* xr = reinterpret_cast<const ushort4*>(x + (long)row * Dc);
    const ushort4 u0 = xr[l], u1 = xr[l + 64], u2 = xr[l + 128];
    float v[12];
    v[0]=bf2f(u0.x); v[1]=bf2f(u0.y); v[2]=bf2f(u0.z); v[3]=bf2f(u0.w);
    v[4]=bf2f(u1.x); v[5]=bf2f(u1.y); v[6]=bf2f(u1.z); v[7]=bf2f(u1.w);
    v[8]=bf2f(u2.x); v[9]=bf2f(u2.y); v[10]=bf2f(u2.z); v[11]=bf2f(u2.w);
    float s = 0.f, q = 0.f;
    #pragma unroll
    for (int e = 0; e < 12; e++) { s += v[e]; q += v[e] * v[e]; }
    #pragma unroll
    for (int o = 1; o < 64; o <<= 1) { s += __shfl_xor(s, o); q += __shfl_xor(q, o); }
    const float mu   = s * (1.0f / Dc);
    const float var  = fmaxf(q * (1.0f / Dc) - mu * mu, 0.0f);
    const float rstd = 1.0f / sqrtf(var + 1e-5f);
    const float4* Ga = reinterpret_cast<const float4*>(cln + (long)t * 2 * Dc);
    const float4* Be = reinterpret_cast<const float4*>(cln + (long)t * 2 * Dc + Dc);
    ushort4* orow = reinterpret_cast<ushort4*>(out + (long)row * Dc);
    #pragma unroll
    for (int c = 0; c < 3; c++) {
        const float4 g = Ga[l + c * 64], be = Be[l + c * 64];
        bf16x4 o;
        o[0] = (__bf16)(g.x * ((v[c*4+0] - mu) * rstd) + be.x);
        o[1] = (__bf16)(g.y * ((v[c*4+1] - mu) * rstd) + be.y);
        o[2] = (__bf16)(g.z * ((v[c*4+2] - mu) * rstd) + be.z);
        o[3] = (__bf16)(g.w * ((v[c*4+3] - mu) * rstd) + be.w);
        orow[l + c * 64] = __builtin_bit_cast(ushort4, o);
    }
}

// ---------------- bf16 TN MFMA GEMM, m97-style pipelined staging -----------
// (unchanged from round 8 — proven at <131 us/dispatch)
template<int DOGELU, int RESM, int OUTF32, int ATASK>
__global__ __launch_bounds__(256, 2) void gemm_tn(
    const __bf16* __restrict__ A, long sA, int lda,
    const __bf16* __restrict__ B, long sB, int ldb,
    const void* __restrict__ R, long sR,
    void* __restrict__ C, long sC, int ldc,
    const int* __restrict__ tasks, int M, int N, int K)
{
    constexpr int BM = 128, BN = 128, BK = 64;
    constexpr int BUFB = 32768;                 // bytes per buffer: A 16K + B 16K
    __shared__ uint4 lds4[2 * BUFB / 16];       // 64 KB
    char* lbase = (char*)lds4;

    const int b = blockIdx.z;
    const int t = tasks[b];
    const __bf16* Ab = A + (ATASK ? (long)t : (long)b) * sA;
    const __bf16* Bb = B + (ATASK ? (long)b : (long)t) * sB;
    const int m0 = blockIdx.y * BM, n0 = blockIdx.x * BN;
    const int tid = threadIdx.x, lane = tid & 63, wid = tid >> 6;
    const int wm = (wid >> 1) * 64, wn = (wid & 1) * 64;
    const int l15 = lane & 15, l4 = lane >> 4;

    f32x4 acc[4][4];
    #pragma unroll
    for (int i = 0; i < 4; i++)
        #pragma unroll
        for (int j = 0; j < 4; j++)
            acc[i][j] = (f32x4){0.f, 0.f, 0.f, 0.f};

    auto STAGE = [&](int k0, int buf) {
        char* dst = lbase + buf * BUFB;
        #pragma unroll
        for (int rep = 0; rep < 4; rep++) {
            const int c = rep * 256 + tid;
            const int m = c >> 3, ch = c & 7;
            const int gk = k0 + ((ch ^ (m & 7)) << 3);
            gload16(Ab + (long)(m0 + m) * lda + gk, dst + c * 16);
        }
        #pragma unroll
        for (int rep = 0; rep < 4; rep++) {
            const int c = rep * 256 + tid;
            const int n = c >> 3, ch = c & 7;
            const int gk = k0 + ((ch ^ (n & 7)) << 3);
            gload16(Bb + (long)(n0 + n) * ldb + gk, dst + 16384 + c * 16);
        }
    };

    const int nt = K / BK;
    STAGE(0, 0);
    __syncthreads();
    int cur = 0;
    for (int tt = 0; tt < nt; tt++) {
        if (tt + 1 < nt) STAGE((tt + 1) * BK, cur ^ 1);
        const char* bb = lbase + cur * BUFB;
        #pragma unroll
        for (int h = 0; h < 2; h++) {
            bf16x8 af[4], bfr[4];
            #pragma unroll
            for (int i = 0; i < 4; i++) {
                const int row = wm + i * 16 + l15;
                af[i] = *reinterpret_cast<const bf16x8*>(
                    bb + row * 128 + (((h * 4 + l4) ^ (l15 & 7)) << 4));
            }
            #pragma unroll
            for (int j = 0; j < 4; j++) {
                const int row = wn + j * 16 + l15;
                bfr[j] = *reinterpret_cast<const bf16x8*>(
                    bb + 16384 + row * 128 + (((h * 4 + l4) ^ (l15 & 7)) << 4));
            }
            #pragma unroll
            for (int i = 0; i < 4; i++)
                #pragma unroll
                for (int j = 0; j < 4; j++)
                    acc[i][j] = __builtin_amdgcn_mfma_f32_16x16x32_bf16(af[i], bfr[j], acc[i][j], 0, 0, 0);
        }
        __syncthreads();
        cur ^= 1;
    }

    float*  Cf = (float*)C  + (long)b * sC;
    __bf16* Ch = (__bf16*)C + (long)b * sC;
    const float*  Rf = (RESM == 1) ? ((const float*)R  + (long)b * sR) : nullptr;
    const __bf16* Rh = (RESM == 2) ? ((const __bf16*)R + (long)b * sR) : nullptr;

    #pragma unroll
    for (int i = 0; i < 4; i++) {
        #pragma unroll
        for (int j = 0; j < 4; j++) {
            const int gn = n0 + wn + j * 16 + l15;
            #pragma unroll
            for (int r = 0; r < 4; r++) {
                const int gm = m0 + wm + i * 16 + l4 * 4 + r;
                float v = acc[i][j][r];
                if (DOGELU) v = 0.5f * v * (1.0f + erff(v * 0.70710678118654752f));
                if (RESM == 1) v += Rf[(long)gm * ldc + gn];
                if (RESM == 2) v += (float)Rh[(long)gm * ldc + gn];
                if (OUTF32) Cf[(long)gm * ldc + gn] = v;
                else        Ch[(long)gm * ldc + gn] = (__bf16)v;
            }
        }
    }
}

extern "C" void kernel_launch(void* const* d_in, const int* in_sizes, int n_in,
                              void* d_out, int out_size, void* d_ws, size_t ws_size,
                              hipStream_t stream) {
    const float* x      = (const float*)d_in[0];
    const int*   tasks  = (const int*)  d_in[1];
    const float* cln1   = (const float*)d_in[2];
    const float* cln2   = (const float*)d_in[3];
    const float* w1_tok = (const float*)d_in[4];
    const float* w2_tok = (const float*)d_in[5];
    const float* w1_ch  = (const float*)d_in[6];
    const float* w2_ch  = (const float*)d_in[7];
    float* out = (float*)d_out;

    // ---- workspace layout (bytes) ----
    char* ws = (char*)d_ws;
    const long oT1 = 0;                               // wT1: 10 x ISp x Sc
    const long oT2 = oT1 + (long)10 * ISp * Sc * 2;   // wT2: 10 x Sc x ISp
    const long oC1 = oT2 + (long)10 * Sc * ISp * 2;   // wC1: 10 x IDp x Dc
    const long oC2 = oC1 + (long)10 * IDp * Dc * 2;   // wC2: 10 x Dc x IDp
    const long oA  = oC2 + (long)10 * Dc * IDp * 2;   // slab: h1T then x1 (B*D*S bf16)
    const long oG  = oA  + (long)Bc * Dc * Sc * 2;    // gbf
    __bf16* wT1  = (__bf16*)(ws + oT1);
    __bf16* wT2  = (__bf16*)(ws + oT2);
    __bf16* wC1  = (__bf16*)(ws + oC1);
    __bf16* wC2  = (__bf16*)(ws + oC2);
    __bf16* h1T  = (__bf16*)(ws + oA);
    __bf16* x1   = (__bf16*)(ws + oA);                // reuses h1T (dead after GEMM2)
    __bf16* gbf  = (__bf16*)(ws + oG);
    __bf16* h2   = (__bf16*)d_out;                    // bf16 scratch inside d_out

    const dim3 blk(256);
    auto cdiv = [](long a, long b) { return (int)((a + b - 1) / b); };

    // 0) all weight conversions in one launch (task-major, zero-padded)
    cvt_all<<<cdiv(CB3, 256), blk, 0, stream>>>(
        w1_tok, w2_tok, w1_ch, w2_ch, wT1, wT2, wC1, wC2);

    // 1) h1T = condLN(x, cln1)^T   (B, D, S) bf16
    ln1_t<<<dim3(Sc / 32, Bc), blk, 0, stream>>>(x, tasks, cln1, h1T);

    // 2) GT = gelu(h1T @ W1tok[t]^T)   M=768, N=384, K=1024
    gemm_tn<1, 0, 0, 0><<<dim3(ISp / 128, Dc / 128, Bc), blk, 0, stream>>>(
        h1T, (long)Dc * Sc, Sc,
        wT1, (long)ISp * Sc, Sc,
        nullptr, 0,
        gbf, (long)Dc * ISp, ISp,
        tasks, Dc, ISp, Sc);

    // 3) x1 = x + W2tok[t] @ GT^T   M=1024, N=768, K=384 ; fp32 res; bf16 out
    gemm_tn<0, 1, 0, 1><<<dim3(Dc / 128, Sc / 128, Bc), blk, 0, stream>>>(
        wT2, (long)Sc * ISp, ISp,
        gbf, (long)Dc * ISp, ISp,
        x, (long)Sc * Dc,
        x1, (long)Sc * Dc, Dc,
        tasks, Sc, Dc, ISp);

    // 4) h2 = condLN(x1, cln2)  (bf16, in d_out scratch)
    cond_ln_b<<<(Bc * Sc) / 4, blk, 0, stream>>>(x1, tasks, cln2, h2);

    // 5) G2 = gelu(h2 @ W1ch[t]^T)   M=1024, N=256, K=768
    gemm_tn<1, 0, 0, 0><<<dim3(IDp / 128, Sc / 128, Bc), blk, 0, stream>>>(
        h2, (long)Sc * Dc, Dc,
        wC1, (long)IDp * Dc, Dc,
        nullptr, 0,
        gbf, (long)Sc * IDp, IDp,
        tasks, Sc, IDp, Dc);

    // 6) out = x1 + G2 @ W2ch[t]^T   M=1024, N=768, K=256 ; bf16 res; fp32 out
    gemm_tn<0, 2, 1, 0><<<dim3(Dc / 128, Sc / 128, Bc), blk, 0, stream>>>(
        gbf, (long)Sc * IDp, IDp,
        wC2, (long)Dc * IDp, IDp,
        x1, (long)Sc * Dc,
        out, (long)Sc * Dc, Dc,
        tasks, Sc, Dc, IDp);
}

// Round 11
// 461.328 us; speedup vs baseline: 1.7837x; 1.0665x over previous
//
#include <hip/hip_runtime.h>
#include <math.h>

typedef __bf16 bf16x8 __attribute__((ext_vector_type(8)));
typedef __bf16 bf16x4 __attribute__((ext_vector_type(4)));
typedef float  f32x4  __attribute__((ext_vector_type(4)));

constexpr int Bc = 64, Sc = 1024, Dc = 768;
constexpr int ISc = 307, IDc = 230;
constexpr int ISp = 384, IDp = 256;   // padded so every GEMM M,N %128==0 and K %64==0

static __device__ __forceinline__ float bf2f(unsigned short u) {
    return __builtin_bit_cast(float, (unsigned)u << 16);
}

// async global->LDS, 16B per lane, linear LDS dest (wave-uniform base + lane*16)
static __device__ __forceinline__ void gload16(const void* g, void* l) {
    __builtin_amdgcn_global_load_lds(
        (const __attribute__((address_space(1))) void*)g,
        (__attribute__((address_space(3))) void*)l, 16, 0, 0);
}

// ---------------- fused fp32 -> bf16 weight convert (all 4 tensors) --------
constexpr int CH0 = 10 * ISp * (Sc  / 8);   // w1_tok -> wT1 (rows 307->384)
constexpr int CH1 = 10 * Sc  * (ISp / 8);   // w2_tok -> wT2 (cols 307->384)
constexpr int CH2 = 10 * IDp * (Dc  / 8);   // w1_ch  -> wC1 (rows 230->256)
constexpr int CH3 = 10 * Dc  * (IDp / 8);   // w2_ch  -> wC2 (cols 230->256)
constexpr int CB0 = CH0, CB1 = CB0 + CH1, CB2 = CB1 + CH2, CB3 = CB2 + CH3;

__device__ __forceinline__ void cvt_one(
    const float* __restrict__ in, __bf16* __restrict__ out,
    int inrows, int outrows, int incols, int outcols, int c)
{
    const int cpr  = outcols >> 3;
    const int perT = outrows * cpr;
    const int t    = c / perT;
    const int rem  = c - t * perT;
    const int r    = rem / cpr;
    const int cc   = (rem - r * cpr) * 8;
    bf16x8 o;
    if (r < inrows) {
        const float* src = in + ((long)t * inrows + r) * incols + cc;
        #pragma unroll
        for (int e = 0; e < 8; e++)
            o[e] = (cc + e < incols) ? (__bf16)src[e] : (__bf16)0.0f;
    } else {
        #pragma unroll
        for (int e = 0; e < 8; e++) o[e] = (__bf16)0.0f;
    }
    *reinterpret_cast<bf16x8*>(out + ((long)t * outrows + r) * outcols + cc) = o;
}

__global__ __launch_bounds__(256) void cvt_all(
    const float* __restrict__ w1t, const float* __restrict__ w2t,
    const float* __restrict__ w1c, const float* __restrict__ w2c,
    __bf16* __restrict__ o1t, __bf16* __restrict__ o2t,
    __bf16* __restrict__ o1c, __bf16* __restrict__ o2c)
{
    const int c = blockIdx.x * 256 + threadIdx.x;
    if (c < CB0)      cvt_one(w1t, o1t, ISc, ISp, Sc,  Sc,  c);
    else if (c < CB1) cvt_one(w2t, o2t, Sc,  Sc,  ISc, ISp, c - CB0);
    else if (c < CB2) cvt_one(w1c, o1c, IDc, IDp, Dc,  Dc,  c - CB1);
    else if (c < CB3) cvt_one(w2c, o2c, Dc,  Dc,  IDc, IDp, c - CB2);
}

// ---------------- LN1 fused with transpose: x (B,S,D) fp32 -> h1T (B,D,S) bf16
__global__ __launch_bounds__(256) void ln1_t(
    const float* __restrict__ x, const int* __restrict__ tasks,
    const float* __restrict__ cln, __bf16* __restrict__ h1T)
{
    constexpr int RPB = 32, LDT = Dc + 8;          // 776 shorts/row
    __shared__ unsigned short T[RPB * LDT];        // 48.5 KB
    const int b   = blockIdx.y;
    const int t   = tasks[b];
    const int s0  = blockIdx.x * RPB;
    const int tid = threadIdx.x;
    const int wv  = tid >> 6;                      // wave 0..3
    const int l   = tid & 63;

    const float4* Ga = reinterpret_cast<const float4*>(cln + (long)t * 2 * Dc);
    const float4* Be = reinterpret_cast<const float4*>(cln + (long)t * 2 * Dc + Dc);
    const float4 g0 = Ga[l], g1 = Ga[l + 64], g2 = Ga[l + 128];
    const float4 b0 = Be[l], b1 = Be[l + 64], b2 = Be[l + 128];

    #pragma unroll
    for (int rr = 0; rr < 8; rr++) {
        const int r = wv * 8 + rr;
        const float4* xr = reinterpret_cast<const float4*>(x + ((long)b * Sc + s0 + r) * Dc);
        const float4 v0 = xr[l], v1 = xr[l + 64], v2 = xr[l + 128];
        float s = v0.x + v0.y + v0.z + v0.w + v1.x + v1.y + v1.z + v1.w
                + v2.x + v2.y + v2.z + v2.w;
        float q = v0.x*v0.x + v0.y*v0.y + v0.z*v0.z + v0.w*v0.w
                + v1.x*v1.x + v1.y*v1.y + v1.z*v1.z + v1.w*v1.w
                + v2.x*v2.x + v2.y*v2.y + v2.z*v2.z + v2.w*v2.w;
        #pragma unroll
        for (int o = 1; o < 64; o <<= 1) { s += __shfl_xor(s, o); q += __shfl_xor(q, o); }
        const float mu   = s * (1.0f / Dc);
        const float var  = fmaxf(q * (1.0f / Dc) - mu * mu, 0.0f);
        const float rstd = 1.0f / sqrtf(var + 1e-5f);
        unsigned short* tr = &T[r * LDT];
        bf16x4 o0, o1, o2;
        o0[0] = (__bf16)(g0.x * ((v0.x - mu) * rstd) + b0.x);
        o0[1] = (__bf16)(g0.y * ((v0.y - mu) * rstd) + b0.y);
        o0[2] = (__bf16)(g0.z * ((v0.z - mu) * rstd) + b0.z);
        o0[3] = (__bf16)(g0.w * ((v0.w - mu) * rstd) + b0.w);
        o1[0] = (__bf16)(g1.x * ((v1.x - mu) * rstd) + b1.x);
        o1[1] = (__bf16)(g1.y * ((v1.y - mu) * rstd) + b1.y);
        o1[2] = (__bf16)(g1.z * ((v1.z - mu) * rstd) + b1.z);
        o1[3] = (__bf16)(g1.w * ((v1.w - mu) * rstd) + b1.w);
        o2[0] = (__bf16)(g2.x * ((v2.x - mu) * rstd) + b2.x);
        o2[1] = (__bf16)(g2.y * ((v2.y - mu) * rstd) + b2.y);
        o2[2] = (__bf16)(g2.z * ((v2.z - mu) * rstd) + b2.z);
        o2[3] = (__bf16)(g2.w * ((v2.w - mu) * rstd) + b2.w);
        *reinterpret_cast<bf16x4*>(&tr[l * 4])        = o0;
        *reinterpret_cast<bf16x4*>(&tr[256 + l * 4])  = o1;
        *reinterpret_cast<bf16x4*>(&tr[512 + l * 4])  = o2;
    }
    __syncthreads();
    #pragma unroll
    for (int c = 0; c < 3; c++) {
        const int d = tid + c * 256;
        unsigned short tmp[32];
        #pragma unroll
        for (int e = 0; e < 32; e++) tmp[e] = T[e * LDT + d];
        __bf16* dst = h1T + ((long)b * Dc + d) * Sc + s0;
        #pragma unroll
        for (int u = 0; u < 4; u++)
            reinterpret_cast<uint4*>(dst)[u] = reinterpret_cast<const uint4*>(tmp)[u];
    }
}

// ---------------- conditional LayerNorm, bf16 -> bf16, wave-per-row --------
__global__ __launch_bounds__(256) void cond_ln_b(
    const __bf16* __restrict__ x, const int* __restrict__ tasks,
    const float* __restrict__ cln, __bf16* __restrict__ out)
{
    const int row = blockIdx.x * 4 + (threadIdx.x >> 6);   // 4 rows/block
    const int b   = row >> 10;
    const int t   = tasks[b];
    const int l   = threadIdx.x & 63;
    const ushort4* xr = reinterpret_cast<const ushort4*>(x + (long)row * Dc);
    const ushort4 u0 = xr[l], u1 = xr[l + 64], u2 = xr[l + 128];
    float v[12];
    v[0]=bf2f(u0.x); v[1]=bf2f(u0.y); v[2]=bf2f(u0.z); v[3]=bf2f(u0.w);
    v[4]=bf2f(u1.x); v[5]=bf2f(u1.y); v[6]=bf2f(u1.z); v[7]=bf2f(u1.w);
    v[8]=bf2f(u2.x); v[9]=bf2f(u2.y); v[10]=bf2f(u2.z); v[11]=bf2f(u2.w);
    float s = 0.f, q = 0.f;
    #pragma unroll
    for (int e = 0; e < 12; e++) { s += v[e]; q += v[e] * v[e]; }
    #pragma unroll
    for (int o = 1; o < 64; o <<= 1) { s += __shfl_xor(s, o); q += __shfl_xor(q, o); }
    const float mu   = s * (1.0f / Dc);
    const float var  = fmaxf(q * (1.0f / Dc) - mu * mu, 0.0f);
    const float rstd = 1.0f / sqrtf(var + 1e-5f);
    const float4* Ga = reinterpret_cast<const float4*>(cln + (long)t * 2 * Dc);
    const float4* Be = reinterpret_cast<const float4*>(cln + (long)t * 2 * Dc + Dc);
    ushort4* orow = reinterpret_cast<ushort4*>(out + (long)row * Dc);
    #pragma unroll
    for (int c = 0; c < 3; c++) {
        const float4 g = Ga[l + c * 64], be = Be[l + c * 64];
        bf16x4 o;
        o[0] = (__bf16)(g.x * ((v[c*4+0] - mu) * rstd) + be.x);
        o[1] = (__bf16)(g.y * ((v[c*4+1] - mu) * rstd) + be.y);
        o[2] = (__bf16)(g.z * ((v[c*4+2] - mu) * rstd) + be.z);
        o[3] = (__bf16)(g.w * ((v[c*4+3] - mu) * rstd) + be.w);
        orow[l + c * 64] = __builtin_bit_cast(ushort4, o);
    }
}

// ---------------- bf16 TN MFMA GEMM, pipelined staging + XCD swizzle -------
// C[b](MxN) = A(MxK,k-contig) * B(NxK,k-contig)^T.  M%128==N%128==K%64==0.
// T1: bijective XCD-chunked remap — each XCD owns 8 whole batches so a
// batch's tiles (shared A-row-panels / B-col-panels, ~4.4MB working set)
// stay resident in that XCD's 4MB L2. Requires nwg%8==0 (z=64 always).
template<int DOGELU, int RESM, int OUTF32, int ATASK>
__global__ __launch_bounds__(256, 2) void gemm_tn(
    const __bf16* __restrict__ A, long sA, int lda,
    const __bf16* __restrict__ B, long sB, int ldb,
    const void* __restrict__ R, long sR,
    void* __restrict__ C, long sC, int ldc,
    const int* __restrict__ tasks, int M, int N, int K)
{
    constexpr int BM = 128, BN = 128, BK = 64;
    constexpr int BUFB = 32768;                 // bytes per buffer: A 16K + B 16K
    __shared__ uint4 lds4[2 * BUFB / 16];       // 64 KB
    char* lbase = (char*)lds4;

    // ---- XCD-aware remap (dispatch order lin -> xcd = lin%8) ----
    const int gx  = gridDim.x, gy = gridDim.y;
    const int tpb = gx * gy;                    // tiles per batch
    const long lin = blockIdx.x + (long)gx * (blockIdx.y + (long)gy * blockIdx.z);
    const int  xcd  = (int)(lin & 7);
    const long idx  = lin >> 3;
    const int  lb   = (int)(idx / tpb);         // 0..7 local batch on this XCD
    const int  tile = (int)(idx - (long)lb * tpb);
    const int  b    = xcd * 8 + lb;
    const int  m0   = (tile / gx) * BM;
    const int  n0   = (tile % gx) * BN;

    const int t = tasks[b];
    const __bf16* Ab = A + (ATASK ? (long)t : (long)b) * sA;
    const __bf16* Bb = B + (ATASK ? (long)b : (long)t) * sB;
    const int tid = threadIdx.x, lane = tid & 63, wid = tid >> 6;
    const int wm = (wid >> 1) * 64, wn = (wid & 1) * 64;
    const int l15 = lane & 15, l4 = lane >> 4;

    f32x4 acc[4][4];
    #pragma unroll
    for (int i = 0; i < 4; i++)
        #pragma unroll
        for (int j = 0; j < 4; j++)
            acc[i][j] = (f32x4){0.f, 0.f, 0.f, 0.f};

    auto STAGE = [&](int k0, int buf) {
        char* dst = lbase + buf * BUFB;
        #pragma unroll
        for (int rep = 0; rep < 4; rep++) {
            const int c = rep * 256 + tid;
            const int m = c >> 3, ch = c & 7;
            const int gk = k0 + ((ch ^ (m & 7)) << 3);
            gload16(Ab + (long)(m0 + m) * lda + gk, dst + c * 16);
        }
        #pragma unroll
        for (int rep = 0; rep < 4; rep++) {
            const int c = rep * 256 + tid;
            const int n = c >> 3, ch = c & 7;
            const int gk = k0 + ((ch ^ (n & 7)) << 3);
            gload16(Bb + (long)(n0 + n) * ldb + gk, dst + 16384 + c * 16);
        }
    };

    const int nt = K / BK;
    STAGE(0, 0);
    __syncthreads();
    int cur = 0;
    for (int tt = 0; tt < nt; tt++) {
        if (tt + 1 < nt) STAGE((tt + 1) * BK, cur ^ 1);
        const char* bb = lbase + cur * BUFB;
        #pragma unroll
        for (int h = 0; h < 2; h++) {
            bf16x8 af[4], bfr[4];
            #pragma unroll
            for (int i = 0; i < 4; i++) {
                const int row = wm + i * 16 + l15;
                af[i] = *reinterpret_cast<const bf16x8*>(
                    bb + row * 128 + (((h * 4 + l4) ^ (l15 & 7)) << 4));
            }
            #pragma unroll
            for (int j = 0; j < 4; j++) {
                const int row = wn + j * 16 + l15;
                bfr[j] = *reinterpret_cast<const bf16x8*>(
                    bb + 16384 + row * 128 + (((h * 4 + l4) ^ (l15 & 7)) << 4));
            }
            #pragma unroll
            for (int i = 0; i < 4; i++)
                #pragma unroll
                for (int j = 0; j < 4; j++)
                    acc[i][j] = __builtin_amdgcn_mfma_f32_16x16x32_bf16(af[i], bfr[j], acc[i][j], 0, 0, 0);
        }
        __syncthreads();
        cur ^= 1;
    }

    float*  Cf = (float*)C  + (long)b * sC;
    __bf16* Ch = (__bf16*)C + (long)b * sC;
    const float*  Rf = (RESM == 1) ? ((const float*)R  + (long)b * sR) : nullptr;
    const __bf16* Rh = (RESM == 2) ? ((const __bf16*)R + (long)b * sR) : nullptr;

    #pragma unroll
    for (int i = 0; i < 4; i++) {
        #pragma unroll
        for (int j = 0; j < 4; j++) {
            const int gn = n0 + wn + j * 16 + l15;
            #pragma unroll
            for (int r = 0; r < 4; r++) {
                const int gm = m0 + wm + i * 16 + l4 * 4 + r;
                float v = acc[i][j][r];
                if (DOGELU) v = 0.5f * v * (1.0f + erff(v * 0.70710678118654752f));
                if (RESM == 1) v += Rf[(long)gm * ldc + gn];
                if (RESM == 2) v += (float)Rh[(long)gm * ldc + gn];
                if (OUTF32) Cf[(long)gm * ldc + gn] = v;
                else        Ch[(long)gm * ldc + gn] = (__bf16)v;
            }
        }
    }
}

extern "C" void kernel_launch(void* const* d_in, const int* in_sizes, int n_in,
                              void* d_out, int out_size, void* d_ws, size_t ws_size,
                              hipStream_t stream) {
    const float* x      = (const float*)d_in[0];
    const int*   tasks  = (const int*)  d_in[1];
    const float* cln1   = (const float*)d_in[2];
    const float* cln2   = (const float*)d_in[3];
    const float* w1_tok = (const float*)d_in[4];
    const float* w2_tok = (const float*)d_in[5];
    const float* w1_ch  = (const float*)d_in[6];
    const float* w2_ch  = (const float*)d_in[7];
    float* out = (float*)d_out;

    // ---- workspace layout (bytes) ----
    char* ws = (char*)d_ws;
    const long oT1 = 0;                               // wT1: 10 x ISp x Sc
    const long oT2 = oT1 + (long)10 * ISp * Sc * 2;   // wT2: 10 x Sc x ISp
    const long oC1 = oT2 + (long)10 * Sc * ISp * 2;   // wC1: 10 x IDp x Dc
    const long oC2 = oC1 + (long)10 * IDp * Dc * 2;   // wC2: 10 x Dc x IDp
    const long oA  = oC2 + (long)10 * Dc * IDp * 2;   // slab: h1T then x1 (B*D*S bf16)
    const long oG  = oA  + (long)Bc * Dc * Sc * 2;    // gbf
    __bf16* wT1  = (__bf16*)(ws + oT1);
    __bf16* wT2  = (__bf16*)(ws + oT2);
    __bf16* wC1  = (__bf16*)(ws + oC1);
    __bf16* wC2  = (__bf16*)(ws + oC2);
    __bf16* h1T  = (__bf16*)(ws + oA);
    __bf16* x1   = (__bf16*)(ws + oA);                // reuses h1T (dead after GEMM2)
    __bf16* gbf  = (__bf16*)(ws + oG);
    __bf16* h2   = (__bf16*)d_out;                    // bf16 scratch inside d_out

    const dim3 blk(256);
    auto cdiv = [](long a, long b) { return (int)((a + b - 1) / b); };

    // 0) all weight conversions in one launch (task-major, zero-padded)
    cvt_all<<<cdiv(CB3, 256), blk, 0, stream>>>(
        w1_tok, w2_tok, w1_ch, w2_ch, wT1, wT2, wC1, wC2);

    // 1) h1T = condLN(x, cln1)^T   (B, D, S) bf16
    ln1_t<<<dim3(Sc / 32, Bc), blk, 0, stream>>>(x, tasks, cln1, h1T);

    // 2) GT = gelu(h1T @ W1tok[t]^T)   M=768, N=384, K=1024
    gemm_tn<1, 0, 0, 0><<<dim3(ISp / 128, Dc / 128, Bc), blk, 0, stream>>>(
        h1T, (long)Dc * Sc, Sc,
        wT1, (long)ISp * Sc, Sc,
        nullptr, 0,
        gbf, (long)Dc * ISp, ISp,
        tasks, Dc, ISp, Sc);

    // 3) x1 = x + W2tok[t] @ GT^T   M=1024, N=768, K=384 ; fp32 res; bf16 out
    gemm_tn<0, 1, 0, 1><<<dim3(Dc / 128, Sc / 128, Bc), blk, 0, stream>>>(
        wT2, (long)Sc * ISp, ISp,
        gbf, (long)Dc * ISp, ISp,
        x, (long)Sc * Dc,
        x1, (long)Sc * Dc, Dc,
        tasks, Sc, Dc, ISp);

    // 4) h2 = condLN(x1, cln2)  (bf16, in d_out scratch)
    cond_ln_b<<<(Bc * Sc) / 4, blk, 0, stream>>>(x1, tasks, cln2, h2);

    // 5) G2 = gelu(h2 @ W1ch[t]^T)   M=1024, N=256, K=768
    gemm_tn<1, 0, 0, 0><<<dim3(IDp / 128, Sc / 128, Bc), blk, 0, stream>>>(
        h2, (long)Sc * Dc, Dc,
        wC1, (long)IDp * Dc, Dc,
        nullptr, 0,
        gbf, (long)Sc * IDp, IDp,
        tasks, Sc, IDp, Dc);

    // 6) out = x1 + G2 @ W2ch[t]^T   M=1024, N=768, K=256 ; bf16 res; fp32 out
    gemm_tn<0, 2, 1, 0><<<dim3(Dc / 128, Sc / 128, Bc), blk, 0, stream>>>(
        gbf, (long)Sc * IDp, IDp,
        wC2, (long)Dc * IDp, IDp,
        x1, (long)Sc * Dc,
        out, (long)Sc * Dc, Dc,
        tasks, Sc, Dc, IDp);
}